// Round 1
// baseline (37.499 us; speedup 1.0000x reference)
//
#include <hip/hip_runtime.h>

// Post_process_deconv: out = depth + sum_k w[k] * (weight[k] - mean_k(weight)) *
//                           bilinear(depth, y - 1 + kh + dy_k, x - 1 + kw + dx_k) + b
// Shapes: depth [B,1,H,W], weight [B,9,H,W], offset [B,18,H,W], w [1,1,3,3], b [1]
// B=2, H=352, W=1216, K=3, pad=1. All fp32.

#define KK 3
#define K2 9
#define PAD 1
#define BB 2
#define HH 352
#define WW 1216

__global__ __launch_bounds__(256) void ppd_kernel(
    const float* __restrict__ depth,   // [B, H*W]
    const float* __restrict__ weight,  // [B, 9, H*W]
    const float* __restrict__ offset,  // [B, 18, H*W]
    const float* __restrict__ wk,      // [9]
    const float* __restrict__ bias,    // [1]
    float* __restrict__ out)           // [B, H*W]
{
    constexpr int HW = HH * WW;
    constexpr int total = BB * HW;
    int idx = blockIdx.x * blockDim.x + threadIdx.x;
    if (idx >= total) return;

    int b  = idx / HW;          // compile-time constant divisor -> magic mul
    int hw = idx - b * HW;
    int y  = hw / WW;
    int x  = hw - y * WW;

    const float* dimg = depth  + (size_t)b * HW;
    const float* wgt  = weight + (size_t)b * (K2 * HW) + hw;
    const float* off  = offset + (size_t)b * (2 * K2 * HW) + hw;

    // Load 9 weights (coalesced, one plane at a time), compute mean.
    float wv[K2];
    float wsum = 0.f;
#pragma unroll
    for (int k = 0; k < K2; ++k) {
        wv[k] = wgt[k * HW];
        wsum += wv[k];
    }
    const float wmean = wsum * (1.0f / 9.0f);

    float acc = 0.f;
#pragma unroll
    for (int k = 0; k < K2; ++k) {
        const float dy = off[(2 * k)     * HW];
        const float dx = off[(2 * k + 1) * HW];
        const int kh = k / KK;
        const int kw = k - kh * KK;
        const float py = (float)(y - PAD + kh) + dy;
        const float px = (float)(x - PAD + kw) + dx;

        const float y0f = floorf(py);
        const float x0f = floorf(px);
        const float ly = py - y0f;
        const float lx = px - x0f;
        const int y0 = (int)y0f;
        const int x0 = (int)x0f;
        const int y1 = y0 + 1;
        const int x1 = x0 + 1;

        const bool yv0 = (y0 >= 0) & (y0 < HH);
        const bool yv1 = (y1 >= 0) & (y1 < HH);
        const bool xv0 = (x0 >= 0) & (x0 < WW);
        const bool xv1 = (x1 >= 0) & (x1 < WW);

        const int y0c = min(max(y0, 0), HH - 1);
        const int y1c = min(max(y1, 0), HH - 1);
        const int x0c = min(max(x0, 0), WW - 1);
        const int x1c = min(max(x1, 0), WW - 1);

        // Clamped addresses are always in-bounds; zero-out invalid taps.
        const float v00 = (yv0 & xv0) ? dimg[y0c * WW + x0c] : 0.f;
        const float v01 = (yv0 & xv1) ? dimg[y0c * WW + x1c] : 0.f;
        const float v10 = (yv1 & xv0) ? dimg[y1c * WW + x0c] : 0.f;
        const float v11 = (yv1 & xv1) ? dimg[y1c * WW + x1c] : 0.f;

        const float s = (1.f - ly) * (1.f - lx) * v00
                      + (1.f - ly) * lx         * v01
                      + ly         * (1.f - lx) * v10
                      + ly         * lx         * v11;

        acc = fmaf(wk[k] * (wv[k] - wmean), s, acc);
    }

    out[idx] = acc + bias[0] + dimg[hw];
}

extern "C" void kernel_launch(void* const* d_in, const int* in_sizes, int n_in,
                              void* d_out, int out_size, void* d_ws, size_t ws_size,
                              hipStream_t stream) {
    const float* depth  = (const float*)d_in[0];
    const float* weight = (const float*)d_in[1];
    const float* offset = (const float*)d_in[2];
    const float* wk     = (const float*)d_in[3];
    const float* bias   = (const float*)d_in[4];
    float* out = (float*)d_out;

    constexpr int total = BB * HH * WW;
    const int block = 256;
    const int grid = (total + block - 1) / block;
    ppd_kernel<<<grid, block, 0, stream>>>(depth, weight, offset, wk, bias, out);
}